// Round 9
// baseline (394.058 us; speedup 1.0000x reference)
//
#include <hip/hip_runtime.h>
#include <math.h>

#define SEQ    512
#define EMB    1024
#define NHEAD  16
#define DHEAD  64
#define NBAT   4
#define QSCALE 0.125f   // 1/sqrt(64)
#define KS     72       // attn K-tile row stride (ushorts)
#define VS     40       // attn V/P tile row stride (ushorts)

typedef __attribute__((ext_vector_type(8))) short bf16x8;
typedef __attribute__((ext_vector_type(4))) float f32x4;

#define MFMA16(a, b, c) __builtin_amdgcn_mfma_f32_16x16x32_bf16(a, b, c, 0, 0, 0)

__device__ __forceinline__ unsigned short f2b(float x) {
  union { float f; unsigned int u; } a; a.f = x;
  unsigned int u = a.u;
  unsigned int r = (u + 0x7fffu + ((u >> 16) & 1u)) >> 16;   // RNE
  return (unsigned short)r;
}
__device__ __forceinline__ unsigned short f2b_fast(float x) {
  union { float f; unsigned int u; } a; a.f = x;
  return (unsigned short)((a.u + 0x8000u) >> 16);            // round-half-up
}
__device__ __forceinline__ float b2f(unsigned short x) {
  union { unsigned int u; float f; } a; a.u = ((unsigned int)x) << 16; return a.f;
}

// async global->LDS 16B: lds dst is wave-uniform base (+ lane*16 by HW)
__device__ __forceinline__ void async16(const unsigned short* g, unsigned short* lds) {
  __builtin_amdgcn_global_load_lds(
      (const __attribute__((address_space(1))) unsigned int*)g,
      (__attribute__((address_space(3))) unsigned int*)lds, 16, 0, 0);
}

// packed sign-based split of bf16x8 into positive/negative parts (exact)
__device__ __forceinline__ void clamp_pn8(bf16x8 x, bf16x8* p, bf16x8* n) {
  const unsigned int* xu = (const unsigned int*)&x;
  unsigned int* pp = (unsigned int*)p;
  unsigned int* nn = (unsigned int*)n;
#pragma unroll
  for (int e = 0; e < 4; e++) {
    const unsigned int s = xu[e] & 0x80008000u;
    const unsigned int mask = s | (s - (s >> 15));   // 0xFFFF in negative halves
    nn[e] = xu[e] & mask;
    pp[e] = xu[e] & ~mask;
  }
}

__device__ __forceinline__ float wave16_sum(float x) {
#pragma unroll
  for (int m = 1; m <= 8; m <<= 1) x += __shfl_xor(x, m);
  return x;
}

// ---------------------------------------------------------------------------
// convert v,l,u fp32 -> bf16 planes Xv, Xc, Xr (all [M][1024])
// ---------------------------------------------------------------------------
__global__ __launch_bounds__(256)
void convert_stack(const float* __restrict__ v, const float* __restrict__ l,
                   const float* __restrict__ u,
                   unsigned short* __restrict__ outV,
                   unsigned short* __restrict__ outC,
                   unsigned short* __restrict__ outR, int total4)
{
  int i = blockIdx.x * 256 + threadIdx.x;
  if (i >= total4) return;
  float4 v4 = ((const float4*)v)[i];
  float4 l4 = ((const float4*)l)[i];
  float4 u4 = ((const float4*)u)[i];
  float lv[4] = {l4.x, l4.y, l4.z, l4.w};
  float uv[4] = {u4.x, u4.y, u4.z, u4.w};
  float vv[4] = {v4.x, v4.y, v4.z, v4.w};
  ushort4 ov, oc, orr;
  unsigned short* pv = (unsigned short*)&ov;
  unsigned short* pc = (unsigned short*)&oc;
  unsigned short* pr = (unsigned short*)&orr;
#pragma unroll
  for (int e = 0; e < 4; e++) {
    pv[e] = f2b(vv[e]);
    pc[e] = f2b(0.5f * (lv[e] + uv[e]));
    pr[e] = f2b(0.5f * (uv[e] - lv[e]));
  }
  ((ushort4*)outV)[i] = ov;
  ((ushort4*)outC)[i] = oc;
  ((ushort4*)outR)[i] = orr;
}

// ---------------------------------------------------------------------------
// W [K][N] fp32 -> Wt [N][K] bf16 and Wabs_t [N][K] bf16 (tiled transpose)
// ---------------------------------------------------------------------------
__global__ __launch_bounds__(256)
void wt_convert(const float* __restrict__ W,
                unsigned short* __restrict__ Wt,
                unsigned short* __restrict__ Wa, int K, int N)
{
  __shared__ float tile[32][33];
  const int n0 = blockIdx.x * 32, k0 = blockIdx.y * 32;
  const int tx = threadIdx.x, ty = threadIdx.y;   // 32 x 8
#pragma unroll
  for (int r = 0; r < 32; r += 8)
    tile[ty + r][tx] = W[(size_t)(k0 + ty + r) * N + n0 + tx];
  __syncthreads();
#pragma unroll
  for (int r = 0; r < 32; r += 8) {
    const float w = tile[tx][ty + r];
    const size_t o = (size_t)(n0 + ty + r) * K + k0 + tx;
    Wt[o] = f2b(w);
    Wa[o] = f2b(fabsf(w));
  }
}

// ---------------------------------------------------------------------------
// Fused IBP projection GEMM v2: A-fragments loaded DIRECTLY global->VGPR
// (k-major layout makes lane frags 16B-contiguous; 64B/row cachelines).
// Only B (weights) staged via double-buffered async16 LDS.
//   v = Av@Bt + b ; l = Ac@Bt - Ar@Ba + b ; u = Ac@Bt + Ar@Ba + b
// 2x2 waves; wave tile = (BM/2) x (BN/2). One barrier per k-iter.
// ---------------------------------------------------------------------------
template<int BM, int BN>
__global__ __launch_bounds__(256)
void gemm_ibp3(const unsigned short* __restrict__ Av,
               const unsigned short* __restrict__ Ac,
               const unsigned short* __restrict__ Ar,
               const unsigned short* __restrict__ Bt,
               const unsigned short* __restrict__ Ba,
               int K, const float* __restrict__ bias,
               float* __restrict__ oV, float* __restrict__ oL, float* __restrict__ oU,
               unsigned short* __restrict__ hV, unsigned short* __restrict__ hL,
               unsigned short* __restrict__ hU,
               unsigned short* __restrict__ vtV, unsigned short* __restrict__ vtL,
               unsigned short* __restrict__ vtU, int N)
{
  constexpr int MI = BM / 32;   // m-frags per wave
  constexpr int NJ = BN / 32;   // n-frags per wave
  __shared__ __attribute__((aligned(16))) unsigned short Bts[2][BN * 32];
  __shared__ __attribute__((aligned(16))) unsigned short Bas[2][BN * 32];

  const int t = threadIdx.x, lane = t & 63, w = t >> 6;
  const int m0 = blockIdx.y * BM, n0 = blockIdx.x * BN;
  const int wm = w & 1, wn = w >> 1;
  const int quad = lane >> 4, r16 = lane & 15;
  const int srow = lane >> 2, sseg = lane & 3;

  f32x4 av[MI][NJ], ac[MI][NJ], ar[MI][NJ];
#pragma unroll
  for (int i = 0; i < MI; i++)
#pragma unroll
    for (int j = 0; j < NJ; j++) {
      av[i][j] = (f32x4){0.f, 0.f, 0.f, 0.f};
      ac[i][j] = (f32x4){0.f, 0.f, 0.f, 0.f};
      ar[i][j] = (f32x4){0.f, 0.f, 0.f, 0.f};
    }

  const int iters = K >> 5;
  auto stage = [&](int it, int buf) {
    const int k0 = it * 32;
#pragma unroll
    for (int r = 0; r < BN / 64; r++) {
      const int brow = (BN / 4) * w + 16 * r;
      const size_t gb = (size_t)(n0 + brow + srow) * K + k0 + sseg * 8;
      async16(Bt + gb, &Bts[buf][brow * 32]);
      async16(Ba + gb, &Bas[buf][brow * 32]);
    }
  };

  stage(0, 0);
  for (int it = 0; it < iters; ++it) {
    const int cur = it & 1;
    const int k0 = it * 32;
    // A fragments straight from global; latency hides under the barrier drain
    bf16x8 fv[MI], fc[MI], fr[MI];
#pragma unroll
    for (int i = 0; i < MI; i++) {
      const size_t ga = (size_t)(m0 + wm * (BM / 2) + i * 16 + r16) * K + k0 + quad * 8;
      fv[i] = *(const bf16x8*)(Av + ga);
      fc[i] = *(const bf16x8*)(Ac + ga);
      fr[i] = *(const bf16x8*)(Ar + ga);
    }
    __syncthreads();                       // drains cur's B staging (all waves)
    if (it + 1 < iters) stage(it + 1, cur ^ 1);
    bf16x8 gt[NJ], gb_[NJ];
#pragma unroll
    for (int j = 0; j < NJ; j++) {
      const int off = (wn * (BN / 2) + j * 16 + r16) * 32 + quad * 8;
      gt[j]  = *(const bf16x8*)(&Bts[cur][off]);
      gb_[j] = *(const bf16x8*)(&Bas[cur][off]);
    }
#pragma unroll
    for (int i = 0; i < MI; i++)
#pragma unroll
      for (int j = 0; j < NJ; j++) {
        av[i][j] = MFMA16(fv[i], gt[j], av[i][j]);
        ac[i][j] = MFMA16(fc[i], gt[j], ac[i][j]);
        ar[i][j] = MFMA16(fr[i], gb_[j], ar[i][j]);
      }
  }

  // epilogue: C/D layout col=lane&15, row=quad*4+reg
#pragma unroll
  for (int i = 0; i < MI; i++) {
    const int mbase = m0 + wm * (BM / 2) + i * 16 + quad * 4;
#pragma unroll
    for (int j = 0; j < NJ; j++) {
      const int n = n0 + wn * (BN / 2) + j * 16 + r16;
      const float bv = bias[n];
      float vv[4], lv[4], uv[4];
#pragma unroll
      for (int rI = 0; rI < 4; rI++) {
        const float c = ac[i][j][rI], r = ar[i][j][rI];
        vv[rI] = av[i][j][rI] + bv;
        lv[rI] = c - r + bv;
        uv[rI] = c + r + bv;
      }
      if (hV) {
#pragma unroll
        for (int rI = 0; rI < 4; rI++) {
          hV[(size_t)(mbase + rI) * N + n] = f2b(vv[rI]);
          hL[(size_t)(mbase + rI) * N + n] = f2b(lv[rI]);
          hU[(size_t)(mbase + rI) * N + n] = f2b(uv[rI]);
        }
      } else {
#pragma unroll
        for (int rI = 0; rI < 4; rI++) {
          oV[(size_t)(mbase + rI) * N + n] = vv[rI];
          oL[(size_t)(mbase + rI) * N + n] = lv[rI];
          oU[(size_t)(mbase + rI) * N + n] = uv[rI];
        }
      }
      if (vtV && n >= 2048) {
        const int hh = (n - 2048) >> 6, dd = (n - 2048) & 63;
        const int bb = mbase >> 9, ss = mbase & 511;
        ushort4 v4, l4, u4;
        unsigned short* vp = (unsigned short*)&v4;
        unsigned short* lp = (unsigned short*)&l4;
        unsigned short* up = (unsigned short*)&u4;
#pragma unroll
        for (int rI = 0; rI < 4; rI++) {
          vp[rI] = f2b(vv[rI]); lp[rI] = f2b(lv[rI]); up[rI] = f2b(uv[rI]);
        }
        const size_t vo = (size_t)((bb * 16 + hh) * 64 + dd) * 512 + ss;
        *(ushort4*)(vtV + vo) = v4;
        *(ushort4*)(vtL + vo) = l4;
        *(ushort4*)(vtU + vo) = u4;
      }
    }
  }
}

// ---------------------------------------------------------------------------
// one 16x16 S sub-tile: 18 MFMA over K=64 (value 2, lb 8, ub 8)
// ---------------------------------------------------------------------------
__device__ __forceinline__ void qk_tile(const unsigned short* K0,
                                        const unsigned short* K1,
                                        const unsigned short* K2,
                                        int cl, int quad,
                                        const bf16x8 qvf[2], const bf16x8 qlpf[2],
                                        const bf16x8 qlnf[2], const bf16x8 qupf[2],
                                        const bf16x8 qunf[2],
                                        f32x4* avp, f32x4* alp, f32x4* aup)
{
  f32x4 v = {0.f, 0.f, 0.f, 0.f}, l = v, u = v;
#pragma unroll
  for (int kh = 0; kh < 2; kh++) {
    const int off = cl * KS + kh * 32 + quad * 8;
    bf16x8 kv = *(const bf16x8*)(K0 + off);
    bf16x8 kl = *(const bf16x8*)(K1 + off);
    bf16x8 ku = *(const bf16x8*)(K2 + off);
    bf16x8 klp, kln, kup, kun;
    clamp_pn8(kl, &klp, &kln);
    clamp_pn8(ku, &kup, &kun);
    v = MFMA16(qvf[kh], kv, v);
    l = MFMA16(qlpf[kh], klp, l);
    l = MFMA16(qupf[kh], kln, l);
    l = MFMA16(qlnf[kh], kup, l);
    l = MFMA16(qunf[kh], kun, l);
    u = MFMA16(qupf[kh], kup, u);
    u = MFMA16(qlpf[kh], kun, u);
    u = MFMA16(qunf[kh], klp, u);
    u = MFMA16(qlnf[kh], kln, u);
  }
  *avp = v; *alp = l; *aup = u;
}

// ---------------------------------------------------------------------------
// MFMA IBP attention v3 (unchanged from R8)
// ---------------------------------------------------------------------------
__global__ __launch_bounds__(256, 4)
void ibp_attn_mfma(const unsigned short* __restrict__ qkv_v,
                   const unsigned short* __restrict__ qkv_l,
                   const unsigned short* __restrict__ qkv_u,
                   const unsigned short* __restrict__ vt_v,
                   const unsigned short* __restrict__ vt_l,
                   const unsigned short* __restrict__ vt_u,
                   unsigned short* __restrict__ Ov,
                   unsigned short* __restrict__ Oc,
                   unsigned short* __restrict__ Or)
{
  __shared__ __attribute__((aligned(16))) unsigned short pool[6912 + 7680 + 3840];
  __shared__ float st[2][32][3];
  unsigned short* Ks = pool;                 // 3 planes, stride 2304
  unsigned short* Vs = pool + 6912;          // 3 planes, stride 2560
  unsigned short* Ps = pool + 6912 + 7680;   // 3 planes, stride 1280

  const int qblk = blockIdx.x, h = blockIdx.y, b = blockIdx.z;
  const int t = threadIdx.x, lane = t & 63, w = t >> 6;
  const int wm = w >> 1, wc = w & 1;
  const int quad = lane >> 4, r16 = lane & 15;
  const int mq = b * SEQ + qblk * 32;
  const int bh = b * NHEAD + h;

  bf16x8 qvf[2], qlpf[2], qlnf[2], qupf[2], qunf[2];
  {
    const size_t qrow = (size_t)(mq + wm * 16 + r16) * 3072 + h * 64;
#pragma unroll
    for (int kh = 0; kh < 2; kh++) {
      bf16x8 v8 = *(const bf16x8*)(qkv_v + qrow + kh * 32 + quad * 8);
      bf16x8 l8 = *(const bf16x8*)(qkv_l + qrow + kh * 32 + quad * 8);
      bf16x8 u8 = *(const bf16x8*)(qkv_u + qrow + kh * 32 + quad * 8);
      const unsigned short* vs = (const unsigned short*)&v8;
      const unsigned short* ls = (const unsigned short*)&l8;
      const unsigned short* us = (const unsigned short*)&u8;
      unsigned short* ov = (unsigned short*)&qvf[kh];
      unsigned short* lp = (unsigned short*)&qlpf[kh];
      unsigned short* ln = (unsigned short*)&qlnf[kh];
      unsigned short* up = (unsigned short*)&qupf[kh];
      unsigned short* un = (unsigned short*)&qunf[kh];
#pragma unroll
      for (int e = 0; e < 8; e++) {
        ov[e] = f2b(b2f(vs[e]) * QSCALE);
        const float lf = b2f(ls[e]) * QSCALE;
        const float uf = b2f(us[e]) * QSCALE;
        lp[e] = f2b(fmaxf(lf, 0.f)); ln[e] = f2b(fminf(lf, 0.f));
        up[e] = f2b(fmaxf(uf, 0.f)); un[e] = f2b(fminf(uf, 0.f));
      }
    }
  }

  const int cl = wc * 16 + r16;
  const int krow = t >> 3, kseg = t & 7;
  const int vrow = t >> 2, vseg = t & 3;
  const unsigned short* kplane[3] = {qkv_v, qkv_l, qkv_u};
  const unsigned short* vplane[3] = {vt_v, vt_l, vt_u};

  // ---- pass 1: raw exp row-sums (ping-pong K) ----
  float Svp[4] = {0.f, 0.f, 0.f, 0.f};
  float Slp[4] = {0.f, 0.f, 0.f, 0.f};
  float Sup[4] = {0.f, 0.f, 0.f, 0.f};

#pragma unroll
  for (int pI = 0; pI < 3; pI++)
    *(uint4*)(Ks + pI * 2304 + krow * KS + kseg * 8) =
        *(const uint4*)(kplane[pI] + (size_t)(b * SEQ + krow) * 3072 + 1024 + h * 64 + kseg * 8);
  __syncthreads();

  for (int ct = 0; ct < 16; ct++) {
    const unsigned short* cur = (ct & 1) ? Vs : Ks;
    if (ct < 15) {
      unsigned short* nxt = (ct & 1) ? Ks : Vs;
      const int c0n = (ct + 1) * 32;
#pragma unroll
      for (int pI = 0; pI < 3; pI++)
        *(uint4*)(nxt + pI * 2304 + krow * KS + kseg * 8) =
            *(const uint4*)(kplane[pI] + (size_t)(b * SEQ + c0n + krow) * 3072 + 1024 + h * 64 + kseg * 8);
    }
    f32x4 av, al, au;
    qk_tile(cur, cur + 2304, cur + 4608, cl, quad,
            qvf, qlpf, qlnf, qupf, qunf, &av, &al, &au);
#pragma unroll
    for (int r = 0; r < 4; r++) {
      Svp[r] += __expf(av[r]);
      Slp[r] += __expf(al[r]);
      Sup[r] += __expf(au[r]);
    }
    __syncthreads();
  }

#pragma unroll
  for (int r = 0; r < 4; r++) {
    Svp[r] = wave16_sum(Svp[r]);
    Slp[r] = wave16_sum(Slp[r]);
    Sup[r] = wave16_sum(Sup[r]);
  }
  if (r16 == 0) {
#pragma unroll
    for (int r = 0; r < 4; r++) {
      st[wc][wm * 16 + quad * 4 + r][0] = Svp[r];
      st[wc][wm * 16 + quad * 4 + r][1] = Slp[r];
      st[wc][wm * 16 + quad * 4 + r][2] = Sup[r];
    }
  }
  __syncthreads();
  float rSv4[4], Sl4[4], Su4[4];
#pragma unroll
  for (int r = 0; r < 4; r++) {
    const int row = wm * 16 + quad * 4 + r;
    rSv4[r] = 1.f / (st[0][row][0] + st[1][row][0]);
    Sl4[r]  = st[0][row][1] + st[1][row][1];
    Su4[r]  = st[0][row][2] + st[1][row][2];
  }

  // ---- pass 2: p and P@V (d-split PV) ----
  f32x4 oa[3][2];
#pragma unroll
  for (int bo = 0; bo < 3; bo++)
#pragma unroll
    for (int ds = 0; ds < 2; ds++) oa[bo][ds] = (f32x4){0.f, 0.f, 0.f, 0.f};

  for (int ct = 0; ct < 16; ct++) {
    const int c0 = ct * 32;
    __syncthreads();
#pragma unroll
    for (int pI = 0; pI < 3; pI++) {
      *(uint4*)(Ks + pI * 2304 + krow * KS + kseg * 8) =
          *(const uint4*)(kplane[pI] + (size_t)(b * SEQ + c0 + krow) * 3072 + 1024 + h * 64 + kseg * 8);
      *(uint4*)(Vs + pI * 2560 + vrow * VS + vseg * 8) =
          *(const uint4*)(vplane[pI] + (size_t)(bh * 64 + vrow) * 512 + c0 + vseg * 8);
    }
    __syncthreads();

    f32x4 av, al, au;
    qk_tile(Ks, Ks + 2304, Ks + 4608, cl, quad,
            qvf, qlpf, qlnf, qupf, qunf, &av, &al, &au);
#pragma unroll
    for (int r = 0; r < 4; r++) {
      const float ev = __expf(av[r]);
      const float el = __expf(al[r]);
      const float eu = __expf(au[r]);
      float pl = el * __builtin_amdgcn_rcpf(Su4[r] - eu + el);
      float pu = eu * __builtin_amdgcn_rcpf(Sl4[r] - el + eu);
      pl = fminf(fmaxf(pl, 0.f), 1.f);
      pu = fminf(fmaxf(pu, 0.f), 1.f);
      const float pev = __shfl_xor(ev, 1);
      const float ppl = __shfl_xor(pl, 1);
      const float ppu = __shfl_xor(pu, 1);
      if (!(r16 & 1)) {
        const unsigned int wv = (unsigned int)f2b_fast(ev) | ((unsigned int)f2b_fast(pev) << 16);
        const unsigned int wl = (unsigned int)f2b_fast(pl) | ((unsigned int)f2b_fast(ppl) << 16);
        const unsigned int wu = (unsigned int)f2b_fast(pu) | ((unsigned int)f2b_fast(ppu) << 16);
        const int prow = (wm * 16 + quad * 4 + r) * VS + cl;
        *(unsigned int*)(Ps + prow)        = wv;
        *(unsigned int*)(Ps + 1280 + prow) = wl;
        *(unsigned int*)(Ps + 2560 + prow) = wu;
      }
    }
    __syncthreads();

#pragma unroll
    for (int ds = 0; ds < 2; ds++) {
      const int dsub = wc * 2 + ds;
      const int voff = (dsub * 16 + r16) * VS + quad * 8;
      bf16x8 vv = *(const bf16x8*)(Vs + voff);
      bf16x8 vl = *(const bf16x8*)(Vs + 2560 + voff);
      bf16x8 vu = *(const bf16x8*)(Vs + 5120 + voff);
      bf16x8 vlp, vln, vup, vun;
      clamp_pn8(vl, &vlp, &vln);
      clamp_pn8(vu, &vup, &vun);
      const int arow = (wm * 16 + r16) * VS + quad * 8;
      bf16x8 pav = *(const bf16x8*)(Ps + arow);
      bf16x8 pal = *(const bf16x8*)(Ps + 1280 + arow);
      bf16x8 pau = *(const bf16x8*)(Ps + 2560 + arow);
      oa[0][ds] = MFMA16(pav, vv, oa[0][ds]);
      oa[1][ds] = MFMA16(pal, vlp, oa[1][ds]);
      oa[1][ds] = MFMA16(pau, vln, oa[1][ds]);
      oa[2][ds] = MFMA16(pau, vup, oa[2][ds]);
      oa[2][ds] = MFMA16(pal, vun, oa[2][ds]);
    }
  }

  // ---- epilogue: bf16 stores into Ov / Oc / Or planes [2048][1024] ----
#pragma unroll
  for (int ds = 0; ds < 2; ds++) {
    const int dsub = wc * 2 + ds;
#pragma unroll
    for (int r = 0; r < 4; r++) {
      const size_t row = (size_t)(mq + wm * 16 + quad * 4 + r);
      const int col = h * 64 + dsub * 16 + r16;
      const float ovv = oa[0][ds][r] * rSv4[r];
      const float olv = oa[1][ds][r];
      const float ouv = oa[2][ds][r];
      Ov[row * 1024 + col] = f2b(ovv);
      Oc[row * 1024 + col] = f2b(0.5f * (olv + ouv));
      Or[row * 1024 + col] = f2b(0.5f * (ouv - olv));
    }
  }
}

// ---------------------------------------------------------------------------
extern "C" void kernel_launch(void* const* d_in, const int* in_sizes, int n_in,
                              void* d_out, int out_size, void* d_ws, size_t ws_size,
                              hipStream_t stream)
{
  const float* x_val = (const float*)d_in[0];
  const float* x_lb  = (const float*)d_in[1];
  const float* x_ub  = (const float*)d_in[2];
  const float* Wi    = (const float*)d_in[3];
  const float* bi    = (const float*)d_in[4];
  const float* Wo    = (const float*)d_in[5];
  const float* bo    = (const float*)d_in[6];
  float* out = (float*)d_out;

  // ws layout (~79 MB). Xv/Xc/Xr reused as attn outputs Ov/Oc/Or (bf16).
  char* p = (char*)d_ws;
  unsigned short* Xv  = (unsigned short*)p; p += (size_t)2048 * 1024 * 2;  // then Ov
  unsigned short* Xc  = (unsigned short*)p; p += (size_t)2048 * 1024 * 2;  // then Oc
  unsigned short* Xr  = (unsigned short*)p; p += (size_t)2048 * 1024 * 2;  // then Or
  unsigned short* Wit = (unsigned short*)p; p += (size_t)3072 * 1024 * 2;
  unsigned short* Wia = (unsigned short*)p; p += (size_t)3072 * 1024 * 2;
  unsigned short* Wot = (unsigned short*)p; p += (size_t)1024 * 1024 * 2;
  unsigned short* Woa = (unsigned short*)p; p += (size_t)1024 * 1024 * 2;
  unsigned short* qv  = (unsigned short*)p; p += (size_t)2048 * 3072 * 2;
  unsigned short* ql  = (unsigned short*)p; p += (size_t)2048 * 3072 * 2;
  unsigned short* qu  = (unsigned short*)p; p += (size_t)2048 * 3072 * 2;
  unsigned short* Vtv = (unsigned short*)p; p += (size_t)64 * 64 * 512 * 2;
  unsigned short* Vtl = (unsigned short*)p; p += (size_t)64 * 64 * 512 * 2;
  unsigned short* Vtu = (unsigned short*)p; p += (size_t)64 * 64 * 512 * 2;

  // 1) convert inputs + weights to bf16
  convert_stack<<<2048, 256, 0, stream>>>(x_val, x_lb, x_ub, Xv, Xc, Xr, 524288);
  wt_convert<<<dim3(96, 32), dim3(32, 8), 0, stream>>>(Wi, Wit, Wia, 1024, 3072);
  wt_convert<<<dim3(32, 32), dim3(32, 8), 0, stream>>>(Wo, Wot, Woa, 1024, 1024);

  // 2) in_proj: fused triple GEMM, BM=64 BN=128 -> 768 blocks (3/CU resident)
  gemm_ibp3<64, 128><<<dim3(3072 / 128, 2048 / 64), 256, 0, stream>>>(
      Xv, Xc, Xr, Wit, Wia, 1024, bi,
      nullptr, nullptr, nullptr, qv, ql, qu, Vtv, Vtl, Vtu, 3072);

  // 3) MFMA IBP attention -> bf16 planes Ov/Oc/Or (alias Xv/Xc/Xr)
  ibp_attn_mfma<<<dim3(SEQ / 32, NHEAD, NBAT), 256, 0, stream>>>(
      qv, ql, qu, Vtv, Vtl, Vtu, Xv, Xc, Xr);

  // 4) out_proj: fused triple GEMM, BM=32 BN=64 -> 1024 blocks (4/CU)
  gemm_ibp3<32, 64><<<dim3(1024 / 64, 2048 / 32), 256, 0, stream>>>(
      Xv, Xc, Xr, Wot, Woa, 1024, bo,
      out, out + (size_t)2048 * 1024, out + (size_t)4096 * 1024,
      nullptr, nullptr, nullptr, nullptr, nullptr, nullptr, 1024);
}